// Round 1
// baseline (466.363 us; speedup 1.0000x reference)
//
#include <hip/hip_runtime.h>
#include <hip/hip_bf16.h>

// Problem constants
#define S_LEN 2048
#define D_MODEL 2048
#define N_HEADS 32
#define N_KV 8
#define HEAD_DIM 64
#define KV_DIM (N_KV * HEAD_DIM)   // 512

typedef __bf16 bf16_t;
typedef __attribute__((ext_vector_type(8))) __bf16 bf16x8;
typedef __attribute__((ext_vector_type(4))) float f32x4;

// ---------------------------------------------------------------------------
// Transpose + convert: src [R][C] f32 (row-major) -> dst [C][R] bf16
// ---------------------------------------------------------------------------
__global__ __launch_bounds__(256) void transpose_convert(const float* __restrict__ src,
                                                         __hip_bfloat16* __restrict__ dst,
                                                         int R, int C) {
    __shared__ float tile[32][33];
    const int bx = blockIdx.x * 32;  // col base in src
    const int by = blockIdx.y * 32;  // row base in src
    const int tx = threadIdx.x;      // 0..31
    const int ty = threadIdx.y;      // 0..7
#pragma unroll
    for (int i = 0; i < 32; i += 8)
        tile[ty + i][tx] = src[(size_t)(by + ty + i) * C + bx + tx];
    __syncthreads();
#pragma unroll
    for (int i = 0; i < 32; i += 8)
        dst[(size_t)(bx + ty + i) * R + by + tx] = __float2bfloat16(tile[tx][ty + i]);
}

// ---------------------------------------------------------------------------
// RoPE (in-place on bf16 [S][nh*64]), optional scale folded in (for Q: 1/8)
// ---------------------------------------------------------------------------
__global__ __launch_bounds__(256) void rope_kernel(__hip_bfloat16* __restrict__ t,
                                                   const float* __restrict__ cos_t,
                                                   const float* __restrict__ sin_t,
                                                   int nh, float scale) {
    const int idx = blockIdx.x * blockDim.x + threadIdx.x;  // S*nh*32 total
    const int i = idx & 31;                 // freq index
    const int h = (idx >> 5) % nh;
    const int s = idx / (32 * nh);
    const float c = cos_t[s * 32 + i];
    const float sn = sin_t[s * 32 + i];
    __hip_bfloat16* p = &t[(size_t)s * (nh * HEAD_DIM) + h * HEAD_DIM + 2 * i];
    const float re = __bfloat162float(p[0]);
    const float im = __bfloat162float(p[1]);
    p[0] = __float2bfloat16((re * c - im * sn) * scale);
    p[1] = __float2bfloat16((re * sn + im * c) * scale);
}

// ---------------------------------------------------------------------------
// GEMM: C[M][N] = A[M][K] @ Bt[N][K]^T   (Bt is pre-transposed, bf16)
// A is f32 (converted during staging) or bf16. 128x128 tile, 4 waves, BK=32.
// ---------------------------------------------------------------------------
__device__ inline bf16x8 load8_cvt(const float* p) {
    const float4 a = *reinterpret_cast<const float4*>(p);
    const float4 b = *reinterpret_cast<const float4*>(p + 4);
    bf16x8 r;
    r[0] = (__bf16)a.x; r[1] = (__bf16)a.y; r[2] = (__bf16)a.z; r[3] = (__bf16)a.w;
    r[4] = (__bf16)b.x; r[5] = (__bf16)b.y; r[6] = (__bf16)b.z; r[7] = (__bf16)b.w;
    return r;
}
__device__ inline bf16x8 load8_cvt(const __hip_bfloat16* p) {
    return *reinterpret_cast<const bf16x8*>(p);
}
__device__ inline void storeC(__hip_bfloat16* p, float v) { *p = __float2bfloat16(v); }
__device__ inline void storeC(float* p, float v) { *p = v; }

template <typename AT, typename OutT>
__global__ __launch_bounds__(256) void gemm_bt(const AT* __restrict__ A,
                                               const __hip_bfloat16* __restrict__ Bt,
                                               OutT* __restrict__ C,
                                               int M, int N, int K) {
    __shared__ __align__(16) __bf16 As[128 * 32];
    __shared__ __align__(16) __bf16 Bs[128 * 32];
    const int tid = threadIdx.x;
    const int w = tid >> 6, l = tid & 63;
    const int wr = w >> 1, wc = w & 1;
    const int l4 = l >> 4, l15 = l & 15;
    const int bm = blockIdx.y * 128, bn = blockIdx.x * 128;

    f32x4 acc[4][4];
#pragma unroll
    for (int i = 0; i < 4; ++i)
#pragma unroll
        for (int j = 0; j < 4; ++j) acc[i][j] = (f32x4){0.f, 0.f, 0.f, 0.f};

    for (int k0 = 0; k0 < K; k0 += 32) {
        // stage A and Bt tiles: each thread moves 2x 8 elements of each
#pragma unroll
        for (int p = 0; p < 2; ++p) {
            const int idx = tid + p * 256;
            const int row = idx >> 2;
            const int col = (idx & 3) * 8;
            const bf16x8 va = load8_cvt(&A[(size_t)(bm + row) * K + k0 + col]);
            *reinterpret_cast<bf16x8*>(&As[row * 32 + col]) = va;
            const bf16x8 vb = load8_cvt(&Bt[(size_t)(bn + row) * K + k0 + col]);
            *reinterpret_cast<bf16x8*>(&Bs[row * 32 + col]) = vb;
        }
        __syncthreads();
        bf16x8 a[4], b[4];
#pragma unroll
        for (int mi = 0; mi < 4; ++mi)
            a[mi] = *reinterpret_cast<const bf16x8*>(&As[(wr * 64 + mi * 16 + l15) * 32 + 8 * l4]);
#pragma unroll
        for (int ni = 0; ni < 4; ++ni)
            b[ni] = *reinterpret_cast<const bf16x8*>(&Bs[(wc * 64 + ni * 16 + l15) * 32 + 8 * l4]);
#pragma unroll
        for (int mi = 0; mi < 4; ++mi)
#pragma unroll
            for (int ni = 0; ni < 4; ++ni)
                acc[mi][ni] = __builtin_amdgcn_mfma_f32_16x16x32_bf16(a[mi], b[ni], acc[mi][ni], 0, 0, 0);
        __syncthreads();
    }
    // epilogue: D row = 4*l4 + reg, col = l15
#pragma unroll
    for (int mi = 0; mi < 4; ++mi)
#pragma unroll
        for (int ni = 0; ni < 4; ++ni)
#pragma unroll
            for (int r = 0; r < 4; ++r) {
                const int row = bm + wr * 64 + mi * 16 + l4 * 4 + r;
                const int col = bn + wc * 64 + ni * 16 + l15;
                storeC(&C[(size_t)row * N + col], acc[mi][ni][r]);
            }
}

// ---------------------------------------------------------------------------
// Flash attention, causal, GQA. 4 waves/block, QBLK=64 (16 q-rows per wave),
// KV tiles of 32. Q/K fragments direct from global; V transposed via LDS;
// P via per-wave LDS round-trip. Q is pre-scaled by 1/sqrt(HEAD_DIM).
// ---------------------------------------------------------------------------
__global__ __launch_bounds__(256) void attn_kernel(const __hip_bfloat16* __restrict__ Q,
                                                   const __hip_bfloat16* __restrict__ K,
                                                   const __hip_bfloat16* __restrict__ V,
                                                   __hip_bfloat16* __restrict__ O) {
    const int h = blockIdx.y;
    const int q0 = blockIdx.x * 64;
    const int hkv = h >> 2;  // N_REP = 4
    const int tid = threadIdx.x;
    const int w = tid >> 6, l = tid & 63;
    const int l4 = l >> 4, l15 = l & 15;

    __shared__ __align__(16) __bf16 Vt[HEAD_DIM * 32];   // [d][kv_local]
    __shared__ __align__(16) __bf16 P[4][16 * 32];       // per-wave P tile

    // Q fragments (A operand): row = l15, k = 8*l4+e
    const int qrow = q0 + w * 16 + l15;
    const bf16x8 qa0 = *reinterpret_cast<const bf16x8*>(&Q[(size_t)qrow * D_MODEL + h * HEAD_DIM + 8 * l4]);
    const bf16x8 qa1 = *reinterpret_cast<const bf16x8*>(&Q[(size_t)qrow * D_MODEL + h * HEAD_DIM + 32 + 8 * l4]);

    f32x4 o_acc[4];
#pragma unroll
    for (int i = 0; i < 4; ++i) o_acc[i] = (f32x4){0.f, 0.f, 0.f, 0.f};
    float m_run[4] = {-__builtin_inff(), -__builtin_inff(), -__builtin_inff(), -__builtin_inff()};
    float s_run[4] = {0.f, 0.f, 0.f, 0.f};

    const int nt = q0 / 32 + 2;  // causal: kv tiles up to q0+64
    for (int t = 0; t < nt; ++t) {
        const int kv0 = t * 32;
        __syncthreads();  // protect Vt from overwrite while previous PV in flight
        {   // stage V^T tile: V[kv0..+32)[hkv*64..+64) -> Vt[d][kv]
            const int r = tid >> 3;            // 0..31 kv row
            const int c0 = (tid & 7) * 8;      // 0..56 d col
            const bf16x8 v = *reinterpret_cast<const bf16x8*>(&V[(size_t)(kv0 + r) * KV_DIM + hkv * HEAD_DIM + c0]);
#pragma unroll
            for (int e = 0; e < 8; ++e) Vt[(c0 + e) * 32 + r] = v[e];
        }
        // K fragments (B operand): B[k=dh][j=kv]: lane holds K[kv0+c*16+l15][kh*32+8*l4+e]
        bf16x8 kb[2][2];
#pragma unroll
        for (int c = 0; c < 2; ++c)
#pragma unroll
            for (int kh = 0; kh < 2; ++kh)
                kb[c][kh] = *reinterpret_cast<const bf16x8*>(
                    &K[(size_t)(kv0 + c * 16 + l15) * KV_DIM + hkv * HEAD_DIM + kh * 32 + 8 * l4]);
        __syncthreads();  // Vt ready

        // S = Q K^T (rows: 4*l4+reg, cols: c*16+l15)
        f32x4 s_acc[2];
        const f32x4 fzero = (f32x4){0.f, 0.f, 0.f, 0.f};
#pragma unroll
        for (int c = 0; c < 2; ++c) {
            s_acc[c] = __builtin_amdgcn_mfma_f32_16x16x32_bf16(qa0, kb[c][0], fzero, 0, 0, 0);
            s_acc[c] = __builtin_amdgcn_mfma_f32_16x16x32_bf16(qa1, kb[c][1], s_acc[c], 0, 0, 0);
        }
        // causal mask
#pragma unroll
        for (int c = 0; c < 2; ++c) {
            const int kvg = kv0 + c * 16 + l15;
#pragma unroll
            for (int r = 0; r < 4; ++r) {
                const int qg = q0 + w * 16 + l4 * 4 + r;
                if (kvg > qg) s_acc[c][r] = -__builtin_inff();
            }
        }
        // online softmax
        float p0[4], p1[4];
#pragma unroll
        for (int r = 0; r < 4; ++r) {
            float mx = fmaxf(s_acc[0][r], s_acc[1][r]);
#pragma unroll
            for (int off = 1; off < 16; off <<= 1) mx = fmaxf(mx, __shfl_xor(mx, off, 64));
            const float mnew = fmaxf(m_run[r], mx);
            const float corr = __expf(m_run[r] - mnew);
            m_run[r] = mnew;
            p0[r] = __expf(s_acc[0][r] - mnew);
            p1[r] = __expf(s_acc[1][r] - mnew);
            float rs = p0[r] + p1[r];
#pragma unroll
            for (int off = 1; off < 16; off <<= 1) rs += __shfl_xor(rs, off, 64);
            s_run[r] = s_run[r] * corr + rs;
#pragma unroll
            for (int dt = 0; dt < 4; ++dt) o_acc[dt][r] *= corr;
        }
        // P -> LDS (per-wave, no cross-wave barrier needed)
#pragma unroll
        for (int r = 0; r < 4; ++r) {
            P[w][(l4 * 4 + r) * 32 + l15] = (__bf16)p0[r];
            P[w][(l4 * 4 + r) * 32 + 16 + l15] = (__bf16)p1[r];
        }
        const bf16x8 pa = *reinterpret_cast<const bf16x8*>(&P[w][l15 * 32 + 8 * l4]);
        // PV: o += P @ V
#pragma unroll
        for (int dt = 0; dt < 4; ++dt) {
            const bf16x8 vb = *reinterpret_cast<const bf16x8*>(&Vt[(dt * 16 + l15) * 32 + 8 * l4]);
            o_acc[dt] = __builtin_amdgcn_mfma_f32_16x16x32_bf16(pa, vb, o_acc[dt], 0, 0, 0);
        }
    }
    // epilogue
#pragma unroll
    for (int dt = 0; dt < 4; ++dt)
#pragma unroll
        for (int r = 0; r < 4; ++r) {
            const int qg = q0 + w * 16 + l4 * 4 + r;
            O[(size_t)qg * D_MODEL + h * HEAD_DIM + dt * 16 + l15] =
                __float2bfloat16(o_acc[dt][r] / s_run[r]);
        }
}

// ---------------------------------------------------------------------------
// Launch
// ---------------------------------------------------------------------------
extern "C" void kernel_launch(void* const* d_in, const int* in_sizes, int n_in,
                              void* d_out, int out_size, void* d_ws, size_t ws_size,
                              hipStream_t stream) {
    const float* x  = (const float*)d_in[0];
    const float* wq = (const float*)d_in[1];
    const float* wk = (const float*)d_in[2];
    const float* wv = (const float*)d_in[3];
    const float* wo = (const float*)d_in[4];
    const float* fc = (const float*)d_in[5];
    const float* fs = (const float*)d_in[6];
    float* out = (float*)d_out;

    char* ws = (char*)d_ws;
    __hip_bfloat16* wqt  = (__hip_bfloat16*)(ws);                     // [2048][2048] bf16, 8 MiB
    __hip_bfloat16* wkt  = (__hip_bfloat16*)(ws + (8u  << 20));       // [512][2048], 2 MiB
    __hip_bfloat16* wvt  = (__hip_bfloat16*)(ws + (10u << 20));       // [512][2048], 2 MiB
    __hip_bfloat16* wot  = (__hip_bfloat16*)(ws + (12u << 20));       // [2048][2048], 8 MiB
    __hip_bfloat16* Qb   = (__hip_bfloat16*)(ws + (20u << 20));       // [2048][2048], 8 MiB
    __hip_bfloat16* Kb   = (__hip_bfloat16*)(ws + (28u << 20));       // [2048][512], 2 MiB
    __hip_bfloat16* Vb   = (__hip_bfloat16*)(ws + (30u << 20));       // [2048][512], 2 MiB
    __hip_bfloat16* attn = (__hip_bfloat16*)(ws + (32u << 20));       // [2048][2048], 8 MiB

    const dim3 tb(32, 8);
    transpose_convert<<<dim3(D_MODEL / 32, D_MODEL / 32), tb, 0, stream>>>(wq, wqt, D_MODEL, D_MODEL);
    transpose_convert<<<dim3(KV_DIM  / 32, D_MODEL / 32), tb, 0, stream>>>(wk, wkt, D_MODEL, KV_DIM);
    transpose_convert<<<dim3(KV_DIM  / 32, D_MODEL / 32), tb, 0, stream>>>(wv, wvt, D_MODEL, KV_DIM);
    transpose_convert<<<dim3(D_MODEL / 32, D_MODEL / 32), tb, 0, stream>>>(wo, wot, D_MODEL, D_MODEL);

    // QKV projections (A = x in f32, converted in staging)
    gemm_bt<float, __hip_bfloat16><<<dim3(D_MODEL / 128, S_LEN / 128), 256, 0, stream>>>(x, wqt, Qb, S_LEN, D_MODEL, D_MODEL);
    gemm_bt<float, __hip_bfloat16><<<dim3(KV_DIM  / 128, S_LEN / 128), 256, 0, stream>>>(x, wkt, Kb, S_LEN, KV_DIM, D_MODEL);
    gemm_bt<float, __hip_bfloat16><<<dim3(KV_DIM  / 128, S_LEN / 128), 256, 0, stream>>>(x, wvt, Vb, S_LEN, KV_DIM, D_MODEL);

    // RoPE (scale 1/sqrt(64)=0.125 folded into Q — exact power of two)
    rope_kernel<<<(S_LEN * N_HEADS * 32) / 256, 256, 0, stream>>>(Qb, fc, fs, N_HEADS, 0.125f);
    rope_kernel<<<(S_LEN * N_KV   * 32) / 256, 256, 0, stream>>>(Kb, fc, fs, N_KV, 1.0f);

    // causal GQA flash attention
    attn_kernel<<<dim3(S_LEN / 64, N_HEADS), 256, 0, stream>>>(Qb, Kb, Vb, attn);

    // output projection -> f32 out
    gemm_bt<__hip_bfloat16, float><<<dim3(D_MODEL / 128, S_LEN / 128), 256, 0, stream>>>(attn, wot, out, S_LEN, D_MODEL, D_MODEL);

    (void)in_sizes; (void)n_in; (void)out_size; (void)ws_size;
}

// Round 2
// 382.822 us; speedup vs baseline: 1.2182x; 1.2182x over previous
//
#include <hip/hip_runtime.h>
#include <hip/hip_bf16.h>

#define S_LEN 2048
#define D_MODEL 2048
#define N_HEADS 32
#define N_KV 8
#define HEAD_DIM 64
#define KV_DIM (N_KV * HEAD_DIM)    // 512
#define QKV_N (D_MODEL + 2 * KV_DIM) // 3072

typedef __bf16 bf16_t;
typedef __attribute__((ext_vector_type(8))) __bf16 bf16x8;
typedef __attribute__((ext_vector_type(4))) float f32x4;

// ---------------------------------------------------------------------------
// async global->LDS 16B copy (m97 pattern). LDS dest must be wave-uniform
// base + lane*16.
// ---------------------------------------------------------------------------
__device__ __forceinline__ void gload_lds16(const void* g, void* l) {
    __builtin_amdgcn_global_load_lds(
        (const __attribute__((address_space(1))) unsigned char*)g,
        (__attribute__((address_space(3))) unsigned char*)l,
        16, 0, 0);
}

// ---------------------------------------------------------------------------
// Transpose + convert: src [R][C] f32 -> dst [C][R] bf16
// ---------------------------------------------------------------------------
__global__ __launch_bounds__(256) void transpose_convert(const float* __restrict__ src,
                                                         __hip_bfloat16* __restrict__ dst,
                                                         int R, int C) {
    __shared__ float tile[32][33];
    const int bx = blockIdx.x * 32;
    const int by = blockIdx.y * 32;
    const int tx = threadIdx.x;  // 0..31
    const int ty = threadIdx.y;  // 0..7
#pragma unroll
    for (int i = 0; i < 32; i += 8)
        tile[ty + i][tx] = src[(size_t)(by + ty + i) * C + bx + tx];
    __syncthreads();
#pragma unroll
    for (int i = 0; i < 32; i += 8)
        dst[(size_t)(bx + ty + i) * R + by + tx] = __float2bfloat16(tile[tx][ty + i]);
}

// ---------------------------------------------------------------------------
// f32 -> bf16 convert (vectorized, 8 elems/thread)
// ---------------------------------------------------------------------------
__global__ __launch_bounds__(256) void convert_bf16(const float* __restrict__ src,
                                                    __hip_bfloat16* __restrict__ dst) {
    const int i = (blockIdx.x * 256 + threadIdx.x) * 8;
    const float4 a = *reinterpret_cast<const float4*>(src + i);
    const float4 b = *reinterpret_cast<const float4*>(src + i + 4);
    bf16x8 r;
    r[0] = (__bf16)a.x; r[1] = (__bf16)a.y; r[2] = (__bf16)a.z; r[3] = (__bf16)a.w;
    r[4] = (__bf16)b.x; r[5] = (__bf16)b.y; r[6] = (__bf16)b.z; r[7] = (__bf16)b.w;
    *reinterpret_cast<bf16x8*>(dst + i) = r;
}

// ---------------------------------------------------------------------------
// RoPE in-place on bf16 [S][row_stride], head count nh, scale folded in.
// ---------------------------------------------------------------------------
__global__ __launch_bounds__(256) void rope_kernel(__hip_bfloat16* __restrict__ t,
                                                   const float* __restrict__ cos_t,
                                                   const float* __restrict__ sin_t,
                                                   int nh, int row_stride, float scale) {
    const int idx = blockIdx.x * blockDim.x + threadIdx.x;
    const int i = idx & 31;
    const int h = (idx >> 5) % nh;
    const int s = idx / (32 * nh);
    const float c = cos_t[s * 32 + i];
    const float sn = sin_t[s * 32 + i];
    __hip_bfloat16* p = &t[(size_t)s * row_stride + h * HEAD_DIM + 2 * i];
    const float re = __bfloat162float(p[0]);
    const float im = __bfloat162float(p[1]);
    p[0] = __float2bfloat16((re * c - im * sn) * scale);
    p[1] = __float2bfloat16((re * sn + im * c) * scale);
}

// ---------------------------------------------------------------------------
// V transpose: QKV[s][2560 + hkv*64 + d] -> Vt[(hkv*64+d)][s]
// ---------------------------------------------------------------------------
__global__ __launch_bounds__(256) void transpose_v(const __hip_bfloat16* __restrict__ QKV,
                                                   __hip_bfloat16* __restrict__ Vt) {
    __shared__ __align__(16) __bf16 tile[64][72];
    const int s0 = blockIdx.x * 64;
    const int hkv = blockIdx.y;
    const int tid = threadIdx.x;
    {
        const int r = tid >> 2;
        const int c0 = (tid & 3) * 16;
        const __hip_bfloat16* src = QKV + (size_t)(s0 + r) * QKV_N + D_MODEL + KV_DIM + hkv * HEAD_DIM + c0;
        *reinterpret_cast<bf16x8*>(&tile[r][c0]) = *reinterpret_cast<const bf16x8*>(src);
        *reinterpret_cast<bf16x8*>(&tile[r][c0 + 8]) = *reinterpret_cast<const bf16x8*>(src + 8);
    }
    __syncthreads();
    {
        const int d = tid >> 2;
        const int sc = (tid & 3) * 16;
        bf16x8 o0, o1;
#pragma unroll
        for (int j = 0; j < 8; ++j) { o0[j] = tile[sc + j][d]; o1[j] = tile[sc + 8 + j][d]; }
        __hip_bfloat16* dst = Vt + (size_t)(hkv * HEAD_DIM + d) * S_LEN + s0 + sc;
        *reinterpret_cast<bf16x8*>(dst) = o0;
        *reinterpret_cast<bf16x8*>(dst + 8) = o1;
    }
}

// ---------------------------------------------------------------------------
// GEMM: C[M][N] = A[M][K](bf16) @ Bt[N][K]^T(bf16). 128x128 tile, BK=32,
// 4 waves, global_load_lds staging (m97 structure).
// ---------------------------------------------------------------------------
__device__ inline void storeC(__hip_bfloat16* p, float v) { *p = __float2bfloat16(v); }
__device__ inline void storeC(float* p, float v) { *p = v; }

template <typename OutT>
__global__ __launch_bounds__(256) void gemm_bt(const __hip_bfloat16* __restrict__ A,
                                               const __hip_bfloat16* __restrict__ Bt,
                                               OutT* __restrict__ C,
                                               int M, int N, int K) {
    __shared__ __align__(16) __bf16 As[128 * 32];
    __shared__ __align__(16) __bf16 Bs[128 * 32];
    const int tid = threadIdx.x;
    const int w = tid >> 6, l = tid & 63;
    const int wr = w >> 1, wc = w & 1;
    const int l4 = l >> 4, l15 = l & 15;
    const int bm = blockIdx.y * 128, bn = blockIdx.x * 128;

    f32x4 acc[4][4];
#pragma unroll
    for (int i = 0; i < 4; ++i)
#pragma unroll
        for (int j = 0; j < 4; ++j) acc[i][j] = (f32x4){0.f, 0.f, 0.f, 0.f};

    // per-thread staging slot: idx p*256+tid -> row idx>>2, col (idx&3)*8,
    // LDS elem offset idx*8 (linear; dest = wave-uniform base + lane*16B)
    const int r0 = tid >> 2, c0 = (tid & 3) * 8;

    for (int k0 = 0; k0 < K; k0 += 32) {
#pragma unroll
        for (int p = 0; p < 2; ++p) {
            const int row = p * 64 + r0;
            gload_lds16(&A[(size_t)(bm + row) * K + k0 + c0], &As[(p * 256 + tid) * 8]);
            gload_lds16(&Bt[(size_t)(bn + row) * K + k0 + c0], &Bs[(p * 256 + tid) * 8]);
        }
        __syncthreads();
        bf16x8 a[4], b[4];
#pragma unroll
        for (int mi = 0; mi < 4; ++mi)
            a[mi] = *reinterpret_cast<const bf16x8*>(&As[(wr * 64 + mi * 16 + l15) * 32 + 8 * l4]);
#pragma unroll
        for (int ni = 0; ni < 4; ++ni)
            b[ni] = *reinterpret_cast<const bf16x8*>(&Bs[(wc * 64 + ni * 16 + l15) * 32 + 8 * l4]);
#pragma unroll
        for (int mi = 0; mi < 4; ++mi)
#pragma unroll
            for (int ni = 0; ni < 4; ++ni)
                acc[mi][ni] = __builtin_amdgcn_mfma_f32_16x16x32_bf16(a[mi], b[ni], acc[mi][ni], 0, 0, 0);
        __syncthreads();
    }
#pragma unroll
    for (int mi = 0; mi < 4; ++mi)
#pragma unroll
        for (int ni = 0; ni < 4; ++ni)
#pragma unroll
            for (int r = 0; r < 4; ++r) {
                const int row = bm + wr * 64 + mi * 16 + l4 * 4 + r;
                const int col = bn + wc * 64 + ni * 16 + l15;
                storeC(&C[(size_t)row * N + col], acc[mi][ni][r]);
            }
}

// ---------------------------------------------------------------------------
// Flash attention, causal, GQA. 4 independent waves/block (16 q-rows each),
// KVBLK=64, no __syncthreads in KV loop. K frags direct from global (QKV),
// V frags direct from pre-transposed Vt. P via XOR-swizzled per-wave LDS.
// Q pre-scaled by 1/sqrt(64)*log2(e); softmax in exp2 domain.
// ---------------------------------------------------------------------------
__device__ __forceinline__ int swzP(int row, int col) {
    return row * 64 + (col ^ ((row & 7) << 3));
}

__global__ __launch_bounds__(256) void attn_kernel(const __hip_bfloat16* __restrict__ QKV,
                                                   const __hip_bfloat16* __restrict__ Vt,
                                                   __hip_bfloat16* __restrict__ O) {
    const int h = blockIdx.y;
    const int hkv = h >> 2;
    const int tid = threadIdx.x;
    const int w = tid >> 6, l = tid & 63;
    const int l4 = l >> 4, l15 = l & 15;
    const int q0w = blockIdx.x * 64 + w * 16;

    __shared__ __align__(16) __bf16 P[4][16 * 64];

    // Q A-fragments: row l15, k = 8*l4+e (cols h*64 + ...)
    const __hip_bfloat16* qbase = QKV + (size_t)(q0w + l15) * QKV_N + h * HEAD_DIM + 8 * l4;
    const bf16x8 qa0 = *reinterpret_cast<const bf16x8*>(qbase);
    const bf16x8 qa1 = *reinterpret_cast<const bf16x8*>(qbase + 32);

    f32x4 o_acc[4];
#pragma unroll
    for (int i = 0; i < 4; ++i) o_acc[i] = (f32x4){0.f, 0.f, 0.f, 0.f};
    float m_run[4] = {-__builtin_inff(), -__builtin_inff(), -__builtin_inff(), -__builtin_inff()};
    float s_run[4] = {0.f, 0.f, 0.f, 0.f};

    const int nt = blockIdx.x + 1;  // KV tiles of 64 (uniform per block)
    const __hip_bfloat16* Kbase = QKV + D_MODEL + hkv * HEAD_DIM;     // [s][QKV_N]
    const __hip_bfloat16* Vbase = Vt + (size_t)hkv * HEAD_DIM * S_LEN; // [d][S]

    for (int t = 0; t < nt; ++t) {
        const int kv0 = t * 64;
        // K B-fragments: col c*16+l15 (kv), k = kh*32+8*l4+e (d)
        bf16x8 kb[4][2];
#pragma unroll
        for (int c = 0; c < 4; ++c) {
            const __hip_bfloat16* kp = Kbase + (size_t)(kv0 + c * 16 + l15) * QKV_N + 8 * l4;
            kb[c][0] = *reinterpret_cast<const bf16x8*>(kp);
            kb[c][1] = *reinterpret_cast<const bf16x8*>(kp + 32);
        }
        f32x4 s_acc[4];
        const f32x4 fzero = (f32x4){0.f, 0.f, 0.f, 0.f};
#pragma unroll
        for (int c = 0; c < 4; ++c) {
            s_acc[c] = __builtin_amdgcn_mfma_f32_16x16x32_bf16(qa0, kb[c][0], fzero, 0, 0, 0);
            s_acc[c] = __builtin_amdgcn_mfma_f32_16x16x32_bf16(qa1, kb[c][1], s_acc[c], 0, 0, 0);
        }
        if (t == nt - 1) {  // causal mask (only last tile can cross diagonal)
#pragma unroll
            for (int c = 0; c < 4; ++c) {
                const int kvg = kv0 + c * 16 + l15;
#pragma unroll
                for (int r = 0; r < 4; ++r)
                    if (kvg > q0w + l4 * 4 + r) s_acc[c][r] = -__builtin_inff();
            }
        }
        // online softmax (exp2 domain; rows owned by 16-lane groups)
        float p[4][4];
#pragma unroll
        for (int r = 0; r < 4; ++r) {
            float mx = fmaxf(fmaxf(s_acc[0][r], s_acc[1][r]), fmaxf(s_acc[2][r], s_acc[3][r]));
#pragma unroll
            for (int off = 1; off < 16; off <<= 1) mx = fmaxf(mx, __shfl_xor(mx, off, 64));
            const float mnew = fmaxf(m_run[r], mx);
            const float corr = exp2f(m_run[r] - mnew);
            m_run[r] = mnew;
            float rs = 0.f;
#pragma unroll
            for (int c = 0; c < 4; ++c) { p[c][r] = exp2f(s_acc[c][r] - mnew); rs += p[c][r]; }
#pragma unroll
            for (int off = 1; off < 16; off <<= 1) rs += __shfl_xor(rs, off, 64);
            s_run[r] = s_run[r] * corr + rs;
#pragma unroll
            for (int dt = 0; dt < 4; ++dt) o_acc[dt][r] *= corr;
        }
        // P -> per-wave LDS (XOR-swizzled), then read back as A-fragments
#pragma unroll
        for (int r = 0; r < 4; ++r)
#pragma unroll
            for (int c = 0; c < 4; ++c)
                P[w][swzP(l4 * 4 + r, c * 16 + l15)] = (__bf16)p[c][r];
        const bf16x8 pa0 = *reinterpret_cast<const bf16x8*>(&P[w][swzP(l15, 8 * l4)]);
        const bf16x8 pa1 = *reinterpret_cast<const bf16x8*>(&P[w][swzP(l15, 32 + 8 * l4)]);
        // PV: o += P @ V  (V B-frags from Vt: col dt*16+l15 (d), k = kv)
#pragma unroll
        for (int dt = 0; dt < 4; ++dt) {
            const __hip_bfloat16* vp = Vbase + (size_t)(dt * 16 + l15) * S_LEN + kv0 + 8 * l4;
            const bf16x8 vb0 = *reinterpret_cast<const bf16x8*>(vp);
            const bf16x8 vb1 = *reinterpret_cast<const bf16x8*>(vp + 32);
            o_acc[dt] = __builtin_amdgcn_mfma_f32_16x16x32_bf16(pa0, vb0, o_acc[dt], 0, 0, 0);
            o_acc[dt] = __builtin_amdgcn_mfma_f32_16x16x32_bf16(pa1, vb1, o_acc[dt], 0, 0, 0);
        }
    }
#pragma unroll
    for (int dt = 0; dt < 4; ++dt)
#pragma unroll
        for (int r = 0; r < 4; ++r) {
            const int qg = q0w + l4 * 4 + r;
            O[(size_t)qg * D_MODEL + h * HEAD_DIM + dt * 16 + l15] =
                __float2bfloat16(o_acc[dt][r] / s_run[r]);
        }
}

// ---------------------------------------------------------------------------
// Launch
// ---------------------------------------------------------------------------
extern "C" void kernel_launch(void* const* d_in, const int* in_sizes, int n_in,
                              void* d_out, int out_size, void* d_ws, size_t ws_size,
                              hipStream_t stream) {
    const float* x  = (const float*)d_in[0];
    const float* wq = (const float*)d_in[1];
    const float* wk = (const float*)d_in[2];
    const float* wv = (const float*)d_in[3];
    const float* wo = (const float*)d_in[4];
    const float* fc = (const float*)d_in[5];
    const float* fs = (const float*)d_in[6];
    float* out = (float*)d_out;

    char* ws = (char*)d_ws;
    __hip_bfloat16* wqkvT = (__hip_bfloat16*)(ws);                 // [3072][2048] bf16, 12 MiB
    __hip_bfloat16* woT   = (__hip_bfloat16*)(ws + (12u << 20));   // [2048][2048], 8 MiB
    __hip_bfloat16* attnb = (__hip_bfloat16*)(ws + (20u << 20));   // [2048][2048], 8 MiB (reuses xb slot)
    __hip_bfloat16* xb    = (__hip_bfloat16*)(ws + (28u << 20));   // [2048][2048], 8 MiB
    __hip_bfloat16* QKV   = (__hip_bfloat16*)(ws + (36u << 20));   // [2048][3072], 12 MiB
    __hip_bfloat16* Vt    = (__hip_bfloat16*)(ws + (48u << 20));   // [512][2048], 2 MiB

    const dim3 tb(32, 8);
    transpose_convert<<<dim3(D_MODEL / 32, D_MODEL / 32), tb, 0, stream>>>(wq, wqkvT, D_MODEL, D_MODEL);
    transpose_convert<<<dim3(KV_DIM / 32, D_MODEL / 32), tb, 0, stream>>>(wk, wqkvT + (size_t)D_MODEL * D_MODEL, D_MODEL, KV_DIM);
    transpose_convert<<<dim3(KV_DIM / 32, D_MODEL / 32), tb, 0, stream>>>(wv, wqkvT + (size_t)(D_MODEL + KV_DIM) * D_MODEL, D_MODEL, KV_DIM);
    transpose_convert<<<dim3(D_MODEL / 32, D_MODEL / 32), tb, 0, stream>>>(wo, woT, D_MODEL, D_MODEL);
    convert_bf16<<<(S_LEN * D_MODEL) / (256 * 8), 256, 0, stream>>>(x, xb);

    // fused QKV projection: [2048][3072]
    gemm_bt<__hip_bfloat16><<<dim3(QKV_N / 128, S_LEN / 128), 256, 0, stream>>>(xb, wqkvT, QKV, S_LEN, QKV_N, D_MODEL);

    // RoPE: Q gets 1/sqrt(64)*log2(e) folded (softmax runs in exp2 domain)
    rope_kernel<<<(S_LEN * N_HEADS * 32) / 256, 256, 0, stream>>>(QKV, fc, fs, N_HEADS, QKV_N, 0.125f * 1.44269504f);
    rope_kernel<<<(S_LEN * N_KV * 32) / 256, 256, 0, stream>>>(QKV + D_MODEL, fc, fs, N_KV, QKV_N, 1.0f);

    // V transpose to [hkv*64+d][s]
    transpose_v<<<dim3(S_LEN / 64, N_KV), 256, 0, stream>>>(QKV, Vt);

    // causal GQA flash attention
    attn_kernel<<<dim3(S_LEN / 64, N_HEADS), 256, 0, stream>>>(QKV, Vt, attnb);

    // output projection -> f32
    gemm_bt<float><<<dim3(D_MODEL / 128, S_LEN / 128), 256, 0, stream>>>(attnb, woT, out, S_LEN, D_MODEL, D_MODEL);

    (void)in_sizes; (void)n_in; (void)out_size; (void)ws_size;
}

// Round 3
// 208.926 us; speedup vs baseline: 2.2322x; 1.8323x over previous
//
#include <hip/hip_runtime.h>
#include <hip/hip_bf16.h>

#define S_LEN 2048
#define D_MODEL 2048
#define N_HEADS 32
#define N_KV 8
#define HEAD_DIM 64
#define KV_DIM (N_KV * HEAD_DIM)    // 512
#define QKV_N (D_MODEL + 2 * KV_DIM) // 3072
#define NQB (S_LEN / 64)             // 32 q-blocks of 64 rows

typedef __bf16 bf16_t;
typedef __attribute__((ext_vector_type(8))) __bf16 bf16x8;
typedef __attribute__((ext_vector_type(4))) float f32x4;

// ---------------------------------------------------------------------------
// async global->LDS 16B copy. LDS dest must be wave-uniform base + lane*16.
// ---------------------------------------------------------------------------
__device__ __forceinline__ void gload_lds16(const void* g, void* l) {
    __builtin_amdgcn_global_load_lds(
        (const __attribute__((address_space(1))) unsigned char*)g,
        (__attribute__((address_space(3))) unsigned char*)l,
        16, 0, 0);
}

// ---------------------------------------------------------------------------
// Transpose + convert: src [R][C] f32 -> dst [C][R] bf16
// ---------------------------------------------------------------------------
__global__ __launch_bounds__(256) void transpose_convert(const float* __restrict__ src,
                                                         __hip_bfloat16* __restrict__ dst,
                                                         int R, int C) {
    __shared__ float tile[32][33];
    const int bx = blockIdx.x * 32;
    const int by = blockIdx.y * 32;
    const int tx = threadIdx.x;  // 0..31
    const int ty = threadIdx.y;  // 0..7
#pragma unroll
    for (int i = 0; i < 32; i += 8)
        tile[ty + i][tx] = src[(size_t)(by + ty + i) * C + bx + tx];
    __syncthreads();
#pragma unroll
    for (int i = 0; i < 32; i += 8)
        dst[(size_t)(bx + ty + i) * R + by + tx] = __float2bfloat16(tile[tx][ty + i]);
}

// ---------------------------------------------------------------------------
// f32 -> bf16 convert (8 elems/thread)
// ---------------------------------------------------------------------------
__global__ __launch_bounds__(256) void convert_bf16(const float* __restrict__ src,
                                                    __hip_bfloat16* __restrict__ dst) {
    const int i = (blockIdx.x * 256 + threadIdx.x) * 8;
    const float4 a = *reinterpret_cast<const float4*>(src + i);
    const float4 b = *reinterpret_cast<const float4*>(src + i + 4);
    bf16x8 r;
    r[0] = (__bf16)a.x; r[1] = (__bf16)a.y; r[2] = (__bf16)a.z; r[3] = (__bf16)a.w;
    r[4] = (__bf16)b.x; r[5] = (__bf16)b.y; r[6] = (__bf16)b.z; r[7] = (__bf16)b.w;
    *reinterpret_cast<bf16x8*>(dst + i) = r;
}

// ---------------------------------------------------------------------------
// RoPE in-place on bf16 [S][row_stride]
// ---------------------------------------------------------------------------
__global__ __launch_bounds__(256) void rope_kernel(__hip_bfloat16* __restrict__ t,
                                                   const float* __restrict__ cos_t,
                                                   const float* __restrict__ sin_t,
                                                   int nh, int row_stride, float scale) {
    const int idx = blockIdx.x * blockDim.x + threadIdx.x;
    const int i = idx & 31;
    const int h = (idx >> 5) % nh;
    const int s = idx / (32 * nh);
    const float c = cos_t[s * 32 + i];
    const float sn = sin_t[s * 32 + i];
    __hip_bfloat16* p = &t[(size_t)s * row_stride + h * HEAD_DIM + 2 * i];
    const float re = __bfloat162float(p[0]);
    const float im = __bfloat162float(p[1]);
    p[0] = __float2bfloat16((re * c - im * sn) * scale);
    p[1] = __float2bfloat16((re * sn + im * c) * scale);
}

// ---------------------------------------------------------------------------
// V transpose: QKV[s][2560 + hkv*64 + d] -> Vt[(hkv*64+d)][s]
// ---------------------------------------------------------------------------
__global__ __launch_bounds__(256) void transpose_v(const __hip_bfloat16* __restrict__ QKV,
                                                   __hip_bfloat16* __restrict__ Vt) {
    __shared__ __align__(16) __bf16 tile[64][72];
    const int s0 = blockIdx.x * 64;
    const int hkv = blockIdx.y;
    const int tid = threadIdx.x;
    {
        const int r = tid >> 2;
        const int c0 = (tid & 3) * 16;
        const __hip_bfloat16* src = QKV + (size_t)(s0 + r) * QKV_N + D_MODEL + KV_DIM + hkv * HEAD_DIM + c0;
        *reinterpret_cast<bf16x8*>(&tile[r][c0]) = *reinterpret_cast<const bf16x8*>(src);
        *reinterpret_cast<bf16x8*>(&tile[r][c0 + 8]) = *reinterpret_cast<const bf16x8*>(src + 8);
    }
    __syncthreads();
    {
        const int d = tid >> 2;
        const int sc = (tid & 3) * 16;
        bf16x8 o0, o1;
#pragma unroll
        for (int j = 0; j < 8; ++j) { o0[j] = tile[sc + j][d]; o1[j] = tile[sc + 8 + j][d]; }
        __hip_bfloat16* dst = Vt + (size_t)(hkv * HEAD_DIM + d) * S_LEN + s0 + sc;
        *reinterpret_cast<bf16x8*>(dst) = o0;
        *reinterpret_cast<bf16x8*>(dst + 8) = o1;
    }
}

// ---------------------------------------------------------------------------
// GEMM: C[M][N] = A[M][K](bf16) @ Bt[N][K]^T(bf16). 128x128 tile, BK=32,
// 4 waves, global_load_lds staging (m97 structure).
// ---------------------------------------------------------------------------
__device__ inline void storeC(__hip_bfloat16* p, float v) { *p = __float2bfloat16(v); }
__device__ inline void storeC(float* p, float v) { *p = v; }

template <typename OutT>
__global__ __launch_bounds__(256) void gemm_bt(const __hip_bfloat16* __restrict__ A,
                                               const __hip_bfloat16* __restrict__ Bt,
                                               OutT* __restrict__ C,
                                               int M, int N, int K) {
    __shared__ __align__(16) __bf16 As[128 * 32];
    __shared__ __align__(16) __bf16 Bs[128 * 32];
    const int tid = threadIdx.x;
    const int w = tid >> 6, l = tid & 63;
    const int wr = w >> 1, wc = w & 1;
    const int l4 = l >> 4, l15 = l & 15;
    const int bm = blockIdx.y * 128, bn = blockIdx.x * 128;

    f32x4 acc[4][4];
#pragma unroll
    for (int i = 0; i < 4; ++i)
#pragma unroll
        for (int j = 0; j < 4; ++j) acc[i][j] = (f32x4){0.f, 0.f, 0.f, 0.f};

    const int r0 = tid >> 2, c0 = (tid & 3) * 8;

    for (int k0 = 0; k0 < K; k0 += 32) {
#pragma unroll
        for (int p = 0; p < 2; ++p) {
            const int row = p * 64 + r0;
            gload_lds16(&A[(size_t)(bm + row) * K + k0 + c0], &As[(p * 256 + tid) * 8]);
            gload_lds16(&Bt[(size_t)(bn + row) * K + k0 + c0], &Bs[(p * 256 + tid) * 8]);
        }
        __syncthreads();
        bf16x8 a[4], b[4];
#pragma unroll
        for (int mi = 0; mi < 4; ++mi)
            a[mi] = *reinterpret_cast<const bf16x8*>(&As[(wr * 64 + mi * 16 + l15) * 32 + 8 * l4]);
#pragma unroll
        for (int ni = 0; ni < 4; ++ni)
            b[ni] = *reinterpret_cast<const bf16x8*>(&Bs[(wc * 64 + ni * 16 + l15) * 32 + 8 * l4]);
#pragma unroll
        for (int mi = 0; mi < 4; ++mi)
#pragma unroll
            for (int ni = 0; ni < 4; ++ni)
                acc[mi][ni] = __builtin_amdgcn_mfma_f32_16x16x32_bf16(a[mi], b[ni], acc[mi][ni], 0, 0, 0);
        __syncthreads();
    }
#pragma unroll
    for (int mi = 0; mi < 4; ++mi)
#pragma unroll
        for (int ni = 0; ni < 4; ++ni)
#pragma unroll
            for (int r = 0; r < 4; ++r) {
                const int row = bm + wr * 64 + mi * 16 + l4 * 4 + r;
                const int col = bn + wc * 64 + ni * 16 + l15;
                storeC(&C[(size_t)row * N + col], acc[mi][ni][r]);
            }
}

// ---------------------------------------------------------------------------
// Flash attention v3. Causal, GQA. 4 waves/block, QBLK=64 (16 q-rows/wave).
// Each block processes the balanced q-block pair (x, 31-x): exactly 33 KV
// tiles of 64 per block. K,V staged in LDS (double-buffered, async
// global_load_lds, XOR-swizzled via pre-swizzled global source), shared by
// all 4 waves. Q pre-scaled by 1/sqrt(64)*log2(e); softmax in exp2 domain.
// LDS swizzle: row r (128B), 16B-chunk c stored at chunk (c ^ (r&7)).
// ---------------------------------------------------------------------------
__global__ __launch_bounds__(256) void attn_kernel(const __hip_bfloat16* __restrict__ QKV,
                                                   const __hip_bfloat16* __restrict__ Vt,
                                                   __hip_bfloat16* __restrict__ O) {
    const int h = blockIdx.y;
    const int hkv = h >> 2;
    const int tid = threadIdx.x;
    const int w = tid >> 6, l = tid & 63;
    const int l4 = l >> 4, l15 = l & 15;

    __shared__ __align__(16) __bf16 Ks[2][64 * 64];  // [kv][d] swizzled
    __shared__ __align__(16) __bf16 Vs[2][64 * 64];  // [d][kv] swizzled
    __shared__ __align__(16) __bf16 P[4][16 * 64];   // per-wave P

    const __hip_bfloat16* Kg = QKV + D_MODEL + hkv * HEAD_DIM;          // [s][QKV_N]
    const __hip_bfloat16* Vg = Vt + (size_t)hkv * HEAD_DIM * S_LEN;     // [d][S]

    // stage one 64x64 tile pair (K,V) into buffer `buf`; 2 chunks each per thread
    auto stage = [&](int buf, int kv0) {
#pragma unroll
        for (int p = 0; p < 2; ++p) {
            const int chunk = (w + p * 4) * 64 + l;   // 0..511
            const int r = chunk >> 3;                 // row 0..63
            const int cs = (chunk & 7) ^ (r & 7);     // pre-swizzled source chunk
            gload_lds16(&Kg[(size_t)(kv0 + r) * QKV_N + cs * 8], &Ks[buf][chunk * 8]);
            gload_lds16(&Vg[(size_t)r * S_LEN + kv0 + cs * 8], &Vs[buf][chunk * 8]);
        }
    };

#pragma unroll 1
    for (int half = 0; half < 2; ++half) {
        const int qb = half == 0 ? (int)blockIdx.x : (NQB - 1 - (int)blockIdx.x);
        const int q0w = qb * 64 + w * 16;
        const int nt = qb + 1;

        // Q A-fragments: row l15, k = 8*l4+e
        const __hip_bfloat16* qbase = QKV + (size_t)(q0w + l15) * QKV_N + h * HEAD_DIM + 8 * l4;
        const bf16x8 qa0 = *reinterpret_cast<const bf16x8*>(qbase);
        const bf16x8 qa1 = *reinterpret_cast<const bf16x8*>(qbase + 32);

        f32x4 o_acc[4];
#pragma unroll
        for (int i = 0; i < 4; ++i) o_acc[i] = (f32x4){0.f, 0.f, 0.f, 0.f};
        float m_run[4] = {-__builtin_inff(), -__builtin_inff(), -__builtin_inff(), -__builtin_inff()};
        float s_run[4] = {0.f, 0.f, 0.f, 0.f};

        __syncthreads();    // previous half's readers done before re-staging buf 0
        stage(0, 0);

#pragma unroll 1
        for (int t = 0; t < nt; ++t) {
            __syncthreads();                        // tile t staged (vmcnt drained)
            if (t + 1 < nt) stage((t + 1) & 1, (t + 1) * 64);
            const __bf16* Kb = Ks[t & 1];
            const __bf16* Vb = Vs[t & 1];
            const int kv0 = t * 64;

            // S = Q K^T
            f32x4 s_acc[4];
            const f32x4 fzero = (f32x4){0.f, 0.f, 0.f, 0.f};
#pragma unroll
            for (int cc = 0; cc < 4; ++cc) {
                const int rr = cc * 16 + l15;
                const bf16x8 kb0 = *reinterpret_cast<const bf16x8*>(&Kb[rr * 64 + ((l4 ^ (rr & 7))) * 8]);
                const bf16x8 kb1 = *reinterpret_cast<const bf16x8*>(&Kb[rr * 64 + (((4 + l4) ^ (rr & 7))) * 8]);
                s_acc[cc] = __builtin_amdgcn_mfma_f32_16x16x32_bf16(qa0, kb0, fzero, 0, 0, 0);
                s_acc[cc] = __builtin_amdgcn_mfma_f32_16x16x32_bf16(qa1, kb1, s_acc[cc], 0, 0, 0);
            }
            if (t == nt - 1) {  // causal mask (only last tile crosses diagonal)
#pragma unroll
                for (int cc = 0; cc < 4; ++cc) {
                    const int kvg = kv0 + cc * 16 + l15;
#pragma unroll
                    for (int r = 0; r < 4; ++r)
                        if (kvg > q0w + l4 * 4 + r) s_acc[cc][r] = -__builtin_inff();
                }
            }
            // online softmax (exp2 domain)
            float p[4][4];
#pragma unroll
            for (int r = 0; r < 4; ++r) {
                float mx = fmaxf(fmaxf(s_acc[0][r], s_acc[1][r]), fmaxf(s_acc[2][r], s_acc[3][r]));
#pragma unroll
                for (int off = 1; off < 16; off <<= 1) mx = fmaxf(mx, __shfl_xor(mx, off, 64));
                const float mnew = fmaxf(m_run[r], mx);
                const float corr = exp2f(m_run[r] - mnew);
                m_run[r] = mnew;
                float rs = 0.f;
#pragma unroll
                for (int cc = 0; cc < 4; ++cc) { p[cc][r] = exp2f(s_acc[cc][r] - mnew); rs += p[cc][r]; }
#pragma unroll
                for (int off = 1; off < 16; off <<= 1) rs += __shfl_xor(rs, off, 64);
                s_run[r] = s_run[r] * corr + rs;
#pragma unroll
                for (int dt = 0; dt < 4; ++dt) o_acc[dt][r] *= corr;
            }
            // P -> per-wave LDS (swizzled), read back as A-fragments
#pragma unroll
            for (int r = 0; r < 4; ++r)
#pragma unroll
                for (int cc = 0; cc < 4; ++cc) {
                    const int row = l4 * 4 + r, col = cc * 16 + l15;
                    P[w][row * 64 + (col ^ ((row & 7) << 3))] = (__bf16)p[cc][r];
                }
            const bf16x8 pa0 = *reinterpret_cast<const bf16x8*>(&P[w][l15 * 64 + ((8 * l4) ^ ((l15 & 7) << 3))]);
            const bf16x8 pa1 = *reinterpret_cast<const bf16x8*>(&P[w][l15 * 64 + ((32 + 8 * l4) ^ ((l15 & 7) << 3))]);
            // PV: o += P @ V
#pragma unroll
            for (int dt = 0; dt < 4; ++dt) {
                const int rv = dt * 16 + l15;
                const bf16x8 vb0 = *reinterpret_cast<const bf16x8*>(&Vb[rv * 64 + ((l4 ^ (rv & 7))) * 8]);
                const bf16x8 vb1 = *reinterpret_cast<const bf16x8*>(&Vb[rv * 64 + (((4 + l4) ^ (rv & 7))) * 8]);
                o_acc[dt] = __builtin_amdgcn_mfma_f32_16x16x32_bf16(pa0, vb0, o_acc[dt], 0, 0, 0);
                o_acc[dt] = __builtin_amdgcn_mfma_f32_16x16x32_bf16(pa1, vb1, o_acc[dt], 0, 0, 0);
            }
        }
        // epilogue for this q-block
#pragma unroll
        for (int dt = 0; dt < 4; ++dt)
#pragma unroll
            for (int r = 0; r < 4; ++r) {
                const int qg = q0w + l4 * 4 + r;
                O[(size_t)qg * D_MODEL + h * HEAD_DIM + dt * 16 + l15] =
                    __float2bfloat16(o_acc[dt][r] / s_run[r]);
            }
    }
}

// ---------------------------------------------------------------------------
// Launch
// ---------------------------------------------------------------------------
extern "C" void kernel_launch(void* const* d_in, const int* in_sizes, int n_in,
                              void* d_out, int out_size, void* d_ws, size_t ws_size,
                              hipStream_t stream) {
    const float* x  = (const float*)d_in[0];
    const float* wq = (const float*)d_in[1];
    const float* wk = (const float*)d_in[2];
    const float* wv = (const float*)d_in[3];
    const float* wo = (const float*)d_in[4];
    const float* fc = (const float*)d_in[5];
    const float* fs = (const float*)d_in[6];
    float* out = (float*)d_out;

    char* ws = (char*)d_ws;
    __hip_bfloat16* wqkvT = (__hip_bfloat16*)(ws);                 // [3072][2048] bf16, 12 MiB
    __hip_bfloat16* woT   = (__hip_bfloat16*)(ws + (12u << 20));   // [2048][2048], 8 MiB
    __hip_bfloat16* attnb = (__hip_bfloat16*)(ws + (20u << 20));   // [2048][2048], 8 MiB
    __hip_bfloat16* xb    = (__hip_bfloat16*)(ws + (28u << 20));   // [2048][2048], 8 MiB
    __hip_bfloat16* QKV   = (__hip_bfloat16*)(ws + (36u << 20));   // [2048][3072], 12 MiB
    __hip_bfloat16* Vt    = (__hip_bfloat16*)(ws + (48u << 20));   // [512][2048], 2 MiB

    const dim3 tb(32, 8);
    transpose_convert<<<dim3(D_MODEL / 32, D_MODEL / 32), tb, 0, stream>>>(wq, wqkvT, D_MODEL, D_MODEL);
    transpose_convert<<<dim3(KV_DIM / 32, D_MODEL / 32), tb, 0, stream>>>(wk, wqkvT + (size_t)D_MODEL * D_MODEL, D_MODEL, KV_DIM);
    transpose_convert<<<dim3(KV_DIM / 32, D_MODEL / 32), tb, 0, stream>>>(wv, wqkvT + (size_t)(D_MODEL + KV_DIM) * D_MODEL, D_MODEL, KV_DIM);
    transpose_convert<<<dim3(D_MODEL / 32, D_MODEL / 32), tb, 0, stream>>>(wo, woT, D_MODEL, D_MODEL);
    convert_bf16<<<(S_LEN * D_MODEL) / (256 * 8), 256, 0, stream>>>(x, xb);

    // fused QKV projection: [2048][3072]
    gemm_bt<__hip_bfloat16><<<dim3(QKV_N / 128, S_LEN / 128), 256, 0, stream>>>(xb, wqkvT, QKV, S_LEN, QKV_N, D_MODEL);

    // RoPE: Q gets 1/sqrt(64)*log2(e) folded (softmax in exp2 domain)
    rope_kernel<<<(S_LEN * N_HEADS * 32) / 256, 256, 0, stream>>>(QKV, fc, fs, N_HEADS, QKV_N, 0.125f * 1.44269504f);
    rope_kernel<<<(S_LEN * N_KV * 32) / 256, 256, 0, stream>>>(QKV + D_MODEL, fc, fs, N_KV, QKV_N, 1.0f);

    // V transpose to [hkv*64+d][s]
    transpose_v<<<dim3(S_LEN / 64, N_KV), 256, 0, stream>>>(QKV, Vt);

    // causal GQA flash attention (balanced pairs: 16 x 32 blocks)
    attn_kernel<<<dim3(NQB / 2, N_HEADS), 256, 0, stream>>>(QKV, Vt, attnb);

    // output projection -> f32
    gemm_bt<float><<<dim3(D_MODEL / 128, S_LEN / 128), 256, 0, stream>>>(attnb, woT, out, S_LEN, D_MODEL, D_MODEL);

    (void)in_sizes; (void)n_in; (void)out_size; (void)ws_size;
}